// Round 2
// baseline (1145.517 us; speedup 1.0000x reference)
//
#include <hip/hip_runtime.h>
#include <stdint.h>

typedef uint32_t u32;
typedef unsigned long long u64;

#define NPTS 65536
#define HEADS 8
#define DIM 32
#define HD 256          // HEADS*DIM
#define BSZ 128         // LSH block size
#define NBLK 512        // NPTS/BSZ
#define SCALE_QK 0.17677669529663687f   // 1/sqrt(32)

// ======================= JAX RNG replication =======================
__device__ __forceinline__ u32 rotl32(u32 v, int r){ return (v << r) | (v >> (32 - r)); }

// threefry2x32 with key = (0, 42)  [jax.random.key(42)]
__device__ void threefry2x32_0_42(u32 x0, u32 x1, u32& o0, u32& o1){
  const u32 ks0 = 0u, ks1 = 42u;
  const u32 ks2 = ks0 ^ ks1 ^ 0x1BD11BDAu;
  x0 += ks0; x1 += ks1;
#define TF_RND(r) { x0 += x1; x1 = rotl32(x1, (r)); x1 ^= x0; }
  TF_RND(13) TF_RND(15) TF_RND(26) TF_RND(6)
  x0 += ks1; x1 += ks2 + 1u;
  TF_RND(17) TF_RND(29) TF_RND(16) TF_RND(24)
  x0 += ks2; x1 += ks0 + 2u;
  TF_RND(13) TF_RND(15) TF_RND(26) TF_RND(6)
  x0 += ks0; x1 += ks1 + 3u;
  TF_RND(17) TF_RND(29) TF_RND(16) TF_RND(24)
  x0 += ks1; x1 += ks2 + 4u;
  TF_RND(13) TF_RND(15) TF_RND(26) TF_RND(6)
  x0 += ks2; x1 += ks0 + 5u;
#undef TF_RND
  o0 = x0; o1 = x1;
}

// XLA ErfInv32 (Giles), with w = -log1p(-x*x)
__device__ float erfinv_xla_f32(float x){
  float w = -log1pf(-x * x);
  float p;
  if (w < 5.0f){
    w = w - 2.5f;
    p =            2.81022636e-08f;
    p = fmaf(p, w, 3.43273939e-07f);
    p = fmaf(p, w, -3.5233877e-06f);
    p = fmaf(p, w, -4.39150654e-06f);
    p = fmaf(p, w,  0.00021858087f);
    p = fmaf(p, w, -0.00125372503f);
    p = fmaf(p, w, -0.00417768164f);
    p = fmaf(p, w,  0.246640727f);
    p = fmaf(p, w,  1.50140941f);
  } else {
    w = sqrtf(w) - 3.0f;
    p =            -0.000200214257f;
    p = fmaf(p, w,  0.000100950558f);
    p = fmaf(p, w,  0.00134934322f);
    p = fmaf(p, w, -0.00367342844f);
    p = fmaf(p, w,  0.00573950773f);
    p = fmaf(p, w, -0.0076224613f);
    p = fmaf(p, w,  0.00943887047f);
    p = fmaf(p, w,  1.00167406f);
    p = fmaf(p, w,  2.83297682f);
  }
  return p * x;
}

// jax.random.normal bit path
__device__ float jax_normal_from_bits(u32 bits){
  float f = __uint_as_float((bits >> 9) | 0x3f800000u) - 1.0f;   // [0,1)
  const float mn = -0.99999994f;                                 // nextafter(-1,0) in f32
  float v = fmaf(f, 2.0f, mn);                                   // (1-(-0.99999994f)) rounds to 2.0f
  v = fmaxf(mn, v);
  return 1.41421356237309505f * erfinv_xla_f32(v);
}

// ======================= small setup kernel =======================
__global__ void k_small(const float* __restrict__ Wrpe, float* __restrict__ proj,
                        float* __restrict__ omega){
  int t = threadIdx.x;
  if (t < 16){
    int h = t >> 1, r = t & 1;
    float s = 0.f;
    for (int wi = 0; wi < 3; wi++)
      for (int d = 0; d < 32; d++){
        float w = Wrpe[(r*3 + wi)*HD + h*32 + d];
        s = fmaf(w, w, s);
      }
    omega[t] = s * (1.0f/96.0f);
  } else if (t < 19){
    int j = t - 16;                       // counters (j, j+3)
    u32 a, b;
    threefry2x32_0_42((u32)j, (u32)(j + 3), a, b);
    proj[0*4 + j] = jax_normal_from_bits(a);   // proj row 0
    proj[1*4 + j] = jax_normal_from_bits(b);   // proj row 1
  }
}

// ======================= LSH codes =======================
__global__ void k_codes(const float* __restrict__ coords, const float* __restrict__ proj,
                        float* __restrict__ codes){
  int i = blockIdx.x * blockDim.x + threadIdx.x;
  if (i >= NPTS) return;
  float c0 = coords[i*3+0], c1 = coords[i*3+1], c2 = coords[i*3+2];
  #pragma unroll
  for (int r = 0; r < 2; r++){
    float code = fmaf(c2, proj[r*4+2], fmaf(c1, proj[r*4+1], c0*proj[r*4+0]));
    codes[i*2+r] = code;
  }
}

// ======================= sort: keys, block-bitonic, merges =======================
__global__ void k_keys(const float* __restrict__ codes, int r, u64* __restrict__ A){
  int i = blockIdx.x * blockDim.x + threadIdx.x;
  if (i >= NPTS) return;
  u32 u = __float_as_uint(codes[i*2 + r]);
  u32 key = (u & 0x80000000u) ? ~u : (u | 0x80000000u);   // order-preserving f32->u32
  A[i] = ((u64)key << 32) | (u64)(u32)i;                  // stable: index in low bits
}

__global__ __launch_bounds__(1024) void k_sort1024(u64* __restrict__ A){
  __shared__ u64 sh[1024];
  int t = threadIdx.x;
  int base = blockIdx.x * 1024;
  sh[t] = A[base + t];
  __syncthreads();
  for (int k = 2; k <= 1024; k <<= 1){
    for (int j = k >> 1; j > 0; j >>= 1){
      int ixj = t ^ j;
      if (ixj > t){
        bool up = ((t & k) == 0);
        u64 a = sh[t], b = sh[ixj];
        if ((a > b) == up){ sh[t] = b; sh[ixj] = a; }
      }
      __syncthreads();
    }
  }
  A[base + t] = sh[t];
}

// merge sorted runs of length L=1<<lg (all keys distinct -> strict lower_bound)
__global__ void k_merge(const u64* __restrict__ src, u64* __restrict__ dst, int lg){
  int g = blockIdx.x * blockDim.x + threadIdx.x;
  if (g >= NPTS) return;
  int L = 1 << lg;
  u64 e = src[g];
  int run = g >> lg;
  int partnerBase = (run ^ 1) << lg;
  int mergedBase = (g >> (lg+1)) << (lg+1);
  int pos = g & (L - 1);
  int lo = 0, hi = L;
  while (lo < hi){
    int mid = (lo + hi) >> 1;
    if (src[partnerBase + mid] < e) lo = mid + 1; else hi = mid;
  }
  dst[mergedBase + pos + lo] = e;
}

// ======================= attention (LN1 + QKV recomputed in-kernel) =======================
// one workgroup per (lsh block, head); 128 threads = one query row each
__global__ __launch_bounds__(128) void k_attn(const u64* __restrict__ sorted,
    const float* __restrict__ x, const float* __restrict__ g1, const float* __restrict__ be1,
    const float* __restrict__ coords,
    const float* __restrict__ Wq, const float* __restrict__ Wk, const float* __restrict__ Wv,
    const float* __restrict__ omega, float* __restrict__ aggr){
  __shared__ float k_s[BSZ][33];
  __shared__ float v_s[BSZ][33];
  __shared__ float ps_s[BSZ][2];
  __shared__ float wq_s[32][32], wk_s[32][32], wv_s[32][32];
  __shared__ float g_s[32], b_s[32];

  int b = blockIdx.x >> 3, h = blockIdx.x & 7;
  int t = threadIdx.x;
  int gq = (int)(u32)(sorted[b*BSZ + t] & 0xffffffffull);

  // stage W head-slices + LN params
  for (int idx = t; idx < 1024; idx += 128){
    int c = idx >> 5, d = idx & 31;
    wq_s[c][d] = Wq[c*HD + h*32 + d];
    wk_s[c][d] = Wk[c*HD + h*32 + d];
    wv_s[c][d] = Wv[c*HD + h*32 + d];
  }
  if (t < 32){ g_s[t] = g1[t]; b_s[t] = be1[t]; }

  // own x row -> LayerNorm -> xr
  float xr[32];
  {
    const float4* xp = (const float4*)(x + (size_t)gq*32);
    #pragma unroll
    for (int c4 = 0; c4 < 8; c4++){
      float4 f = xp[c4];
      xr[c4*4+0]=f.x; xr[c4*4+1]=f.y; xr[c4*4+2]=f.z; xr[c4*4+3]=f.w;
    }
  }
  ps_s[t][0] = coords[gq*3+0];
  ps_s[t][1] = coords[gq*3+1];
  __syncthreads();

  {
    float mu = 0.f;
    #pragma unroll
    for (int c = 0; c < 32; c++) mu += xr[c];
    mu *= (1.0f/32.0f);
    float var = 0.f;
    #pragma unroll
    for (int c = 0; c < 32; c++){ float d = xr[c]-mu; var = fmaf(d, d, var); }
    var *= (1.0f/32.0f);
    float rs = rsqrtf(var + 1e-5f);
    #pragma unroll
    for (int c = 0; c < 32; c++) xr[c] = (xr[c]-mu)*rs*g_s[c] + b_s[c];
  }

  // k row -> LDS
  {
    float a2[32];
    #pragma unroll
    for (int d = 0; d < 32; d++) a2[d] = 0.f;
    #pragma unroll
    for (int c = 0; c < 32; c++){
      float xv = xr[c];
      #pragma unroll
      for (int d = 0; d < 32; d++) a2[d] = fmaf(xv, wk_s[c][d], a2[d]);
    }
    #pragma unroll
    for (int d = 0; d < 32; d++) k_s[t][d] = a2[d];
  }
  // v row -> LDS
  {
    float a2[32];
    #pragma unroll
    for (int d = 0; d < 32; d++) a2[d] = 0.f;
    #pragma unroll
    for (int c = 0; c < 32; c++){
      float xv = xr[c];
      #pragma unroll
      for (int d = 0; d < 32; d++) a2[d] = fmaf(xv, wv_s[c][d], a2[d]);
    }
    #pragma unroll
    for (int d = 0; d < 32; d++) v_s[t][d] = a2[d];
  }
  // q row -> regs
  float q[32];
  {
    #pragma unroll
    for (int d = 0; d < 32; d++) q[d] = 0.f;
    #pragma unroll
    for (int c = 0; c < 32; c++){
      float xv = xr[c];
      #pragma unroll
      for (int d = 0; d < 32; d++) q[d] = fmaf(xv, wq_s[c][d], q[d]);
    }
  }
  __syncthreads();

  // flash attention over the 128-row block, chunk = 16
  float om0 = omega[h*2+0], om1 = omega[h*2+1];
  float p0 = ps_s[t][0], p1 = ps_s[t][1];
  float m = -1e30f, l = 0.f;
  float acc[32];
  #pragma unroll
  for (int d = 0; d < 32; d++) acc[d] = 0.f;

  for (int kk0 = 0; kk0 < BSZ; kk0 += 16){
    float s[16];
    #pragma unroll
    for (int j = 0; j < 16; j++){
      int kk = kk0 + j;
      float dot = 0.f;
      #pragma unroll
      for (int c = 0; c < 32; c++) dot = fmaf(q[c], k_s[kk][c], dot);
      float d0 = p0 - ps_s[kk][0];
      float d1 = p1 - ps_s[kk][1];
      float pen = fmaf(om0, d0*d0, om1*(d1*d1));
      s[j] = fmaf(dot, SCALE_QK, -pen);
    }
    float cm = s[0];
    #pragma unroll
    for (int j = 1; j < 16; j++) cm = fmaxf(cm, s[j]);
    float mn = fmaxf(m, cm);
    float corr = __expf(m - mn);
    l *= corr;
    #pragma unroll
    for (int d = 0; d < 32; d++) acc[d] *= corr;
    #pragma unroll
    for (int j = 0; j < 16; j++){
      float pw = __expf(s[j] - mn);
      l += pw;
      #pragma unroll
      for (int c = 0; c < 32; c++) acc[c] = fmaf(pw, v_s[kk0+j][c], acc[c]);
    }
    m = mn;
  }
  float sc = 0.5f / l;   // includes /NH
  float* op = aggr + (size_t)gq*HD + h*32;
  #pragma unroll
  for (int d = 0; d < 32; d++) op[d] += acc[d] * sc;
}

// ======================= Wo projection + residual =======================
__global__ void k_wo(const float* __restrict__ x, const float* __restrict__ aggr,
                     const float* __restrict__ Wo, const float* __restrict__ bo,
                     float* __restrict__ x2){
  int gid = blockIdx.x * blockDim.x + threadIdx.x;    // NPTS*32 threads
  int i = gid >> 5, d = gid & 31;
  if (i >= NPTS) return;
  const float* ar = aggr + (size_t)i*HD;
  float a = 0.f;
  for (int j = 0; j < HD; j++) a = fmaf(ar[j], Wo[j*32 + d], a);
  x2[gid] = x[gid] + a + bo[d];
}

// ======================= LN2 + FFN + residual -> out =======================
__global__ void k_ffn(const float* __restrict__ x2, const float* __restrict__ g2,
                      const float* __restrict__ be2, const float* __restrict__ W1,
                      const float* __restrict__ b1, const float* __restrict__ W2,
                      const float* __restrict__ b2, float* __restrict__ out){
  __shared__ float w1s[1024], w2s[1024], b1s[32], b2s[32], gs[32], bs[32];
  int t = threadIdx.x;
  for (int idx = t; idx < 1024; idx += 256){ w1s[idx] = W1[idx]; w2s[idx] = W2[idx]; }
  if (t < 32){ b1s[t] = b1[t]; b2s[t] = b2[t]; gs[t] = g2[t]; bs[t] = be2[t]; }
  __syncthreads();
  int i = blockIdx.x * blockDim.x + t;
  if (i >= NPTS) return;

  float v[32];
  const float4* xp = (const float4*)(x2 + (size_t)i*32);
  #pragma unroll
  for (int c4 = 0; c4 < 8; c4++){
    float4 f = xp[c4];
    v[c4*4+0]=f.x; v[c4*4+1]=f.y; v[c4*4+2]=f.z; v[c4*4+3]=f.w;
  }
  float mu = 0.f;
  #pragma unroll
  for (int c = 0; c < 32; c++) mu += v[c];
  mu *= (1.0f/32.0f);
  float var = 0.f;
  #pragma unroll
  for (int c = 0; c < 32; c++){ float d = v[c]-mu; var = fmaf(d, d, var); }
  var *= (1.0f/32.0f);
  float rs = rsqrtf(var + 1e-5f);
  float hh[32];
  #pragma unroll
  for (int c = 0; c < 32; c++) hh[c] = (v[c]-mu)*rs*gs[c] + bs[c];

  float t1[32];
  #pragma unroll
  for (int j = 0; j < 32; j++){
    float a = b1s[j];
    #pragma unroll
    for (int c = 0; c < 32; c++) a = fmaf(hh[c], w1s[c*32 + j], a);
    t1[j] = fmaxf(a, 0.f);
  }
  float* op = out + (size_t)i*32;
  #pragma unroll
  for (int d2 = 0; d2 < 32; d2++){
    float o = b2s[d2];
    #pragma unroll
    for (int j = 0; j < 32; j++) o = fmaf(t1[j], w2s[j*32 + d2], o);
    op[d2] = v[d2] + o;
  }
}

// ======================= launch =======================
extern "C" void kernel_launch(void* const* d_in, const int* in_sizes, int n_in,
                              void* d_out, int out_size, void* d_ws, size_t ws_size,
                              hipStream_t stream) {
  (void)in_sizes; (void)n_in; (void)out_size; (void)ws_size;
  const float* x      = (const float*)d_in[0];
  const float* coords = (const float*)d_in[1];
  const float* g1     = (const float*)d_in[2];
  const float* be1    = (const float*)d_in[3];
  const float* Wq     = (const float*)d_in[4];
  const float* Wk     = (const float*)d_in[5];
  const float* Wv     = (const float*)d_in[6];
  const float* Wrpe   = (const float*)d_in[7];
  const float* Wo     = (const float*)d_in[8];
  const float* bo     = (const float*)d_in[9];
  const float* g2     = (const float*)d_in[10];
  const float* be2    = (const float*)d_in[11];
  const float* W1     = (const float*)d_in[12];
  const float* b1     = (const float*)d_in[13];
  const float* W2     = (const float*)d_in[14];
  const float* b2     = (const float*)d_in[15];
  float* out = (float*)d_out;

  char* ws = (char*)d_ws;
  float* aggr  = (float*)(ws + 0);             // 64 MB  (NPTS*HD f32)
  float* codes = (float*)(ws + 67108864);      // 512 KB
  u64*   bufA  = (u64*)  (ws + 67633152);      // 512 KB
  u64*   bufB  = (u64*)  (ws + 68157440);      // 512 KB
  float* proj  = (float*)(ws + 68681728);      // 32 B
  float* omega = (float*)(ws + 68681984);      // 64 B
  float* x2    = out;                          // reuse d_out as x2 scratch (safe: k_ffn
                                               // reads row to regs before overwrite)

  hipMemsetAsync(aggr, 0, (size_t)NPTS*HD*sizeof(float), stream);
  k_small<<<1, 64, 0, stream>>>(Wrpe, proj, omega);
  k_codes<<<NPTS/256, 256, 0, stream>>>(coords, proj, codes);

  for (int r = 0; r < 2; r++){
    k_keys<<<NPTS/256, 256, 0, stream>>>(codes, r, bufA);
    k_sort1024<<<NPTS/1024, 1024, 0, stream>>>(bufA);
    u64 *src = bufA, *dst = bufB;
    for (int lg = 10; lg < 16; lg++){
      k_merge<<<NPTS/256, 256, 0, stream>>>(src, dst, lg);
      u64* tmp = src; src = dst; dst = tmp;
    }
    // 6 passes -> sorted result is in src
    k_attn<<<NBLK*HEADS, 128, 0, stream>>>(src, x, g1, be1, coords, Wq, Wk, Wv, omega, aggr);
  }

  k_wo <<<NPTS*32/256, 256, 0, stream>>>(x, aggr, Wo, bo, x2);
  k_ffn<<<NPTS/256, 256, 0, stream>>>(x2, g2, be2, W1, b1, W2, b2, out);
}